// Round 4
// baseline (306.034 us; speedup 1.0000x reference)
//
#include <hip/hip_runtime.h>
#include <math.h>

typedef __bf16 bf16_t;
typedef __bf16 bf16x8 __attribute__((ext_vector_type(8)));
typedef __bf16 bf16x4 __attribute__((ext_vector_type(4)));
typedef float f32x4 __attribute__((ext_vector_type(4)));

namespace {
constexpr int kB = 16;
constexpr int kT = 120;
constexpr int kP = 96;
constexpr int kD = 128;
constexpr int kBT = kB * kT;        // 1920
constexpr int kPP = kP * kP;        // 9216
constexpr int kPD = kP * kD;        // 12288
constexpr long long kND = (long long)kBT * kPP;  // 17,694,720

// LDS strides (bf16 elements) for k_gcn
constexpr int YS = 136;   // yL  [96][136]  = 26112 B
constexpr int HS = 104;   // hT  [128][104] = 26624 B
constexpr int OS = 132;   // oLb [96][132]  = 25344 B
constexpr int AS = 104;   // aL  [96][104]  = 19968 B
constexpr int UNION_B = 26624;             // max(yL, hT, oLb)
constexpr int AL_OFF = UNION_B;            // 26624
constexpr int PL_OFF = AL_OFF + 19968;     // 46592 (params 3072 B)
constexpr int MROW_OFF = PL_OFF + 3072;    // 49664 (384 B)
constexpr int SMEM_B = MROW_OFF + 384;     // 50048 -> 3 blocks/CU
}

__device__ __forceinline__ f32x4 mfma16(bf16x8 a, bf16x8 b, f32x4 c) {
    return __builtin_amdgcn_mfma_f32_16x16x32_bf16(a, b, c, 0, 0, 0);
}

// LDS-publish barrier WITHOUT the vmcnt(0) drain __syncthreads() would emit:
// waits own LDS ops, then s_barrier. Keeps prefetch global loads in flight.
__device__ __forceinline__ void bar_pub() {
    asm volatile("s_waitcnt lgkmcnt(0)" ::: "memory");
    __builtin_amdgcn_s_barrier();
    __builtin_amdgcn_sched_barrier(0);
}

// ---------------------------------------------------------------------------
// Kernel 1: canonicalize mask (layout-detecting) + zero stats + pack params.
// ---------------------------------------------------------------------------
__global__ void k_mask(const unsigned char* __restrict__ mraw, int* __restrict__ mask,
                       double* __restrict__ stats, const float* __restrict__ bias,
                       const float* __restrict__ gamma, const float* __restrict__ beta,
                       float* __restrict__ ppack) {
    int tid = threadIdx.x;
    if (tid < 4) stats[tid] = 0.0;
    const unsigned int* u32 = (const unsigned int*)mraw;
    unsigned int w0 = u32[0];
    int mode;
    if (w0 == 0x01010101u) mode = 0;       // 1-byte bool
    else if (w0 == 1u) mode = 1;           // int32
    else mode = 2;                          // float32
    for (int i = tid; i < kB * kP; i += blockDim.x) {
        int v;
        if (mode == 0)      v = (mraw[i] != 0);
        else if (mode == 1) v = (u32[i] != 0);
        else                v = (((const float*)mraw)[i] != 0.0f);
        mask[i] = v;
    }
    // ppack[l][which][d], which: 0=bias 1=gamma 2=beta
    for (int i = tid; i < 2 * 3 * kD; i += blockDim.x) {
        int l = i / 384, r = i - l * 384, which = r >> 7, d = r & 127;
        const float* src = which == 0 ? bias : (which == 1 ? gamma : beta);
        ppack[i] = src[l * kD + d];
    }
}

// ---------------------------------------------------------------------------
// Kernel 2: W[l][k][n] (f32) -> wT[l][n][k] (bf16)
// ---------------------------------------------------------------------------
__global__ void k_prep(const float* __restrict__ W, bf16_t* __restrict__ wT) {
    int l = blockIdx.y;
    int idx = blockIdx.x * 256 + threadIdx.x;
    int n = idx >> 7, k = idx & 127;
    wT[l * 16384 + n * 128 + k] = (bf16_t)W[l * 16384 + k * 128 + n];
}

// ---------------------------------------------------------------------------
// Kernel 3: global masked stats over distances (float4 loads, LDS mask).
// ---------------------------------------------------------------------------
__global__ __launch_bounds__(256) void k_stats(const float* __restrict__ dist,
                                               const int* __restrict__ mask,
                                               double* __restrict__ stats) {
    __shared__ int ml[kB * kP];
    for (int i = threadIdx.x; i < kB * kP; i += 256) ml[i] = mask[i];
    __syncthreads();

    long long n4 = kND / 4;
    long long stride = (long long)gridDim.x * 256;
    double s = 0.0, s2 = 0.0;
    int cnt = 0;
    for (long long i4 = (long long)blockIdx.x * 256 + threadIdx.x; i4 < n4; i4 += stride) {
        int q0 = 4 * (int)(i4 % 24);
        long long r = i4 / 24;
        int p = (int)(r % 96);
        int b = (int)((r / 96) / kT);
        const int* mb = ml + b * kP;
        if (mb[p]) {
            float4 d4 = *(const float4*)(dist + i4 * 4);
            if (mb[q0 + 0]) { s += d4.x; s2 += (double)d4.x * d4.x; cnt++; }
            if (mb[q0 + 1]) { s += d4.y; s2 += (double)d4.y * d4.y; cnt++; }
            if (mb[q0 + 2]) { s += d4.z; s2 += (double)d4.z * d4.z; cnt++; }
            if (mb[q0 + 3]) { s += d4.w; s2 += (double)d4.w * d4.w; cnt++; }
        }
    }
    __shared__ double sh[256];
    int tid = threadIdx.x;
    sh[tid] = s; __syncthreads();
    for (int off = 128; off > 0; off >>= 1) { if (tid < off) sh[tid] += sh[tid + off]; __syncthreads(); }
    if (tid == 0) atomicAdd(&stats[0], sh[0]);
    __syncthreads();
    sh[tid] = s2; __syncthreads();
    for (int off = 128; off > 0; off >>= 1) { if (tid < off) sh[tid] += sh[tid + off]; __syncthreads(); }
    if (tid == 0) atomicAdd(&stats[1], sh[0]);
    __syncthreads();
    sh[tid] = (double)cnt; __syncthreads();
    for (int off = 128; off > 0; off >>= 1) { if (tid < off) sh[tid] += sh[tid + off]; __syncthreads(); }
    if (tid == 0) atomicAdd(&stats[2], sh[0]);
}

// ---------------------------------------------------------------------------
// Kernel 4: finalize sigma -> 1/(2*sigma^2)
// ---------------------------------------------------------------------------
__global__ void k_fin(const double* __restrict__ stats, float* __restrict__ params) {
    double n = stats[2];
    double mean = stats[0] / n;
    double var = (stats[1] - n * mean * mean) / (n - 1.0);
    double sigma = sqrt(var) + 1e-8;
    params[0] = (float)(1.0 / (2.0 * sigma * sigma));
}

// ---------------------------------------------------------------------------
// Kernel 5: adjacency build, one block per (b,t). float4 in, bf16x4 out.
// Pre-normalization matrix is exactly symmetric (dist bitwise-symmetric),
// so degree = column sum (conflict-free LDS reads).
// ---------------------------------------------------------------------------
__global__ __launch_bounds__(256) void k_adj(const float* __restrict__ dist,
                                             const int* __restrict__ mask,
                                             const float* __restrict__ params,
                                             bf16_t* __restrict__ adj) {
    __shared__ float aT[kP * 100];
    __shared__ float dis[kP];
    __shared__ float mr[kP];
    int bt = blockIdx.x;
    int b = bt / kT;
    int tid = threadIdx.x;
    if (tid < kP) mr[tid] = (float)mask[b * kP + tid];
    float inv2s2 = params[0];
    __syncthreads();
    const float* dbt = dist + (long long)bt * kPP;
    #pragma unroll
    for (int k = 0; k < 9; ++k) {
        int i4 = k * 256 + tid;          // 0..2303
        int e = i4 * 4;
        int p = e / kP, q = e - p * kP;  // 96 % 4 == 0 -> same row
        float4 d4 = *(const float4*)(dbt + e);
        float mp = mr[p];
        float v[4];
        v[0] = mp * mr[q + 0] != 0.f ? __expf(-d4.x * d4.x * inv2s2) : 0.f;
        v[1] = mp * mr[q + 1] != 0.f ? __expf(-d4.y * d4.y * inv2s2) : 0.f;
        v[2] = mp * mr[q + 2] != 0.f ? __expf(-d4.z * d4.z * inv2s2) : 0.f;
        v[3] = mp * mr[q + 3] != 0.f ? __expf(-d4.w * d4.w * inv2s2) : 0.f;
        #pragma unroll
        for (int j = 0; j < 4; ++j) {
            if (p == q + j) v[j] += mp;
            aT[p * 100 + q + j] = v[j];
        }
    }
    __syncthreads();
    if (tid < kP) {
        float s = 0.f;
        for (int q = 0; q < kP; ++q) s += aT[q * 100 + tid];  // column == row sum
        s = fmaxf(s, 1e-8f);
        s = fmaxf(s * mr[tid], 1e-8f);
        dis[tid] = rsqrtf(s);
    }
    __syncthreads();
    bf16_t* obt = adj + (long long)bt * kPP;
    #pragma unroll
    for (int k = 0; k < 9; ++k) {
        int i4 = k * 256 + tid;
        int e = i4 * 4;
        int p = e / kP, q = e - p * kP;
        float dp = dis[p];
        bf16x4 ov;
        #pragma unroll
        for (int j = 0; j < 4; ++j)
            ov[j] = (bf16_t)(dp * aT[p * 100 + q + j] * dis[q + j]);
        *(bf16x4*)(obt + e) = ov;
    }
}

// ---------------------------------------------------------------------------
// Kernel 6: transpose in, x (B, PD, T) f32 -> y (B, T, PD) bf16.
// Block: 64 pd-rows x full T. float4 reads, bf16x8 writes.
// ---------------------------------------------------------------------------
__global__ __launch_bounds__(256) void k_tin(const float* __restrict__ x,
                                             bf16_t* __restrict__ y) {
    __shared__ float tile[64 * 121];
    int b = blockIdx.y, pd0 = blockIdx.x * 64;
    int tid = threadIdx.x;
    const float* xb = x + ((long long)b * kPD + pd0) * kT;
    #pragma unroll
    for (int k = 0; k < 8; ++k) {
        int idx = k * 256 + tid;               // < 1920 = 64 rows * 30 float4
        if (idx < 1920) {
            int r = idx / 30, c = idx - r * 30;
            float4 v = *(const float4*)(xb + r * kT + c * 4);
            tile[r * 121 + c * 4 + 0] = v.x;
            tile[r * 121 + c * 4 + 1] = v.y;
            tile[r * 121 + c * 4 + 2] = v.z;
            tile[r * 121 + c * 4 + 3] = v.w;
        }
    }
    __syncthreads();
    bf16_t* yb = y + (long long)b * kT * kPD + pd0;
    #pragma unroll
    for (int k = 0; k < 4; ++k) {
        int idx = k * 256 + tid;               // < 960 = 120 t * 8 dgroups
        if (idx < 960) {
            int t = idx >> 3, dg = idx & 7;
            bf16x8 o;
            #pragma unroll
            for (int j = 0; j < 8; ++j) o[j] = (bf16_t)tile[(dg * 8 + j) * 121 + t];
            *(bf16x8*)(yb + (long long)t * kPD + dg * 8) = o;
        }
    }
}

// ---------------------------------------------------------------------------
// Kernel 8: transpose out, y (B, T, PD) bf16 -> out (B, PD, T) f32.
// ---------------------------------------------------------------------------
__global__ __launch_bounds__(256) void k_tout(const bf16_t* __restrict__ y,
                                              float* __restrict__ out) {
    __shared__ float tile[64 * 121];
    int b = blockIdx.y, pd0 = blockIdx.x * 64;
    int tid = threadIdx.x;
    const bf16_t* yb = y + (long long)b * kT * kPD + pd0;
    #pragma unroll
    for (int k = 0; k < 4; ++k) {
        int idx = k * 256 + tid;
        if (idx < 960) {
            int t = idx >> 3, dg = idx & 7;
            bf16x8 v = *(const bf16x8*)(yb + (long long)t * kPD + dg * 8);
            #pragma unroll
            for (int j = 0; j < 8; ++j) tile[(dg * 8 + j) * 121 + t] = (float)v[j];
        }
    }
    __syncthreads();
    float* ob = out + ((long long)b * kPD + pd0) * kT;
    #pragma unroll
    for (int k = 0; k < 8; ++k) {
        int idx = k * 256 + tid;
        if (idx < 1920) {
            int r = idx / 30, c = idx - r * 30;
            float4 v;
            v.x = tile[r * 121 + c * 4 + 0];
            v.y = tile[r * 121 + c * 4 + 1];
            v.z = tile[r * 121 + c * 4 + 2];
            v.w = tile[r * 121 + c * 4 + 3];
            *(float4*)(ob + r * kT + c * 4) = v;
        }
    }
}

// ---------------------------------------------------------------------------
// Kernel 7: fused 2-layer GCN. One block (4 waves) per 2 consecutive bt.
// Cross-tile register prefetch (T14): next bt's adj issued before S1, next
// bt's y issued after GEMM1 -> in flight across layer-0 compute. Raw
// lgkm-only barriers (no vmcnt drain). All epilogue params staged in LDS.
// ---------------------------------------------------------------------------
__global__ __launch_bounds__(256, 3) void k_gcn(bf16_t* __restrict__ y,
                                                const bf16_t* __restrict__ adj,
                                                const int* __restrict__ mask,
                                                const bf16_t* __restrict__ wT,
                                                const float* __restrict__ ppack) {
    __shared__ __align__(16) char smem[SMEM_B];
    bf16_t* yL  = (bf16_t*)smem;                  // [96][YS]   (union)
    bf16_t* hT  = (bf16_t*)smem;                  // [128][HS]  (union)
    bf16_t* oLb = (bf16_t*)smem;                  // [96][OS]   (union)
    bf16_t* aL  = (bf16_t*)(smem + AL_OFF);       // [96][AS]
    float*  pL  = (float*)(smem + PL_OFF);        // [2][3][128]
    float*  mrowf = (float*)(smem + MROW_OFF);    // [96]

    const int tid = threadIdx.x;
    const int tx = tid & 15, ty = tid >> 4;
    const int lane = tid & 63, w = tid >> 6;
    const int fc = lane & 15, fg = lane >> 4;
    const int bt0 = blockIdx.x * 2;
    const int d0 = tx * 8;

    // stage epilogue params -> LDS
    #pragma unroll
    for (int k = 0; k < 3; ++k) pL[k * 256 + tid] = ppack[k * 256 + tid];

    // initial prefetch: bt0's y and adj -> registers
    bf16x8 yP[6];
    bf16x4 aP[9];
    {
        const bf16_t* ybt0 = y + (size_t)bt0 * kPD;
        const bf16_t* abt0 = adj + (size_t)bt0 * kPP;
        #pragma unroll
        for (int i = 0; i < 6; ++i) yP[i] = *(const bf16x8*)(ybt0 + (ty * 6 + i) * kD + d0);
        #pragma unroll
        for (int k = 0; k < 9; ++k) aP[k] = *(const bf16x4*)(abt0 + (k * 256 + tid) * 4);
    }

    for (int s = 0; s < 2; ++s) {
        const int bt = bt0 + s;
        const int b = bt / kT;
        bf16_t* ybt = y + (size_t)bt * kPD;

        if (tid < kP) mrowf[tid] = (float)mask[b * kP + tid];

        // reg -> LDS staging (waits the yP/aP loads via compiler vmcnt)
        #pragma unroll
        for (int k = 0; k < 9; ++k) {
            int e4 = (k * 256 + tid) * 4;
            int p = e4 / kP, q = e4 - p * kP;
            *(bf16x4*)(aL + p * AS + q) = aP[k];
        }
        float res[6][8];
        #pragma unroll
        for (int i = 0; i < 6; ++i) {
            int p = ty * 6 + i;
            #pragma unroll
            for (int j = 0; j < 8; ++j) res[i][j] = (float)yP[i][j];
            *(bf16x8*)(yL + p * YS + d0) = yP[i];
        }

        // W fragments for l=0 (issued BEFORE the adj prefetch so consuming
        // them waits vmcnt(9), not 0)
        bf16x8 wf[4][2];
        #pragma unroll
        for (int kt = 0; kt < 4; ++kt) {
            wf[kt][0] = *(const bf16x8*)(wT + (w * 32 + fc) * kD + kt * 32 + fg * 8);
            wf[kt][1] = *(const bf16x8*)(wT + (w * 32 + 16 + fc) * kD + kt * 32 + fg * 8);
        }
        // prefetch next bt's adj (in flight across all of layer 0)
        if (s == 0) {
            const bf16_t* abt1 = adj + (size_t)(bt0 + 1) * kPP;
            #pragma unroll
            for (int k = 0; k < 9; ++k) aP[k] = *(const bf16x4*)(abt1 + (k * 256 + tid) * 4);
            __builtin_amdgcn_sched_barrier(0);
        }

        for (int l = 0; l < 2; ++l) {
            if (l == 1) {
                const bf16_t* wT1 = wT + kD * kD;
                #pragma unroll
                for (int kt = 0; kt < 4; ++kt) {
                    wf[kt][0] = *(const bf16x8*)(wT1 + (w * 32 + fc) * kD + kt * 32 + fg * 8);
                    wf[kt][1] = *(const bf16x8*)(wT1 + (w * 32 + 16 + fc) * kD + kt * 32 + fg * 8);
                }
            }
            bar_pub();   // S1: yL/aL (or yL restage) visible

            // ---- GEMM1: h = yL * W  (K=128) ----
            f32x4 acc[6][2];
            #pragma unroll
            for (int mt = 0; mt < 6; ++mt) { acc[mt][0] = {0,0,0,0}; acc[mt][1] = {0,0,0,0}; }
            #pragma unroll
            for (int kt = 0; kt < 4; ++kt) {
                #pragma unroll
                for (int mt = 0; mt < 6; ++mt) {
                    bf16x8 af = *(const bf16x8*)(yL + (mt * 16 + fc) * YS + kt * 32 + fg * 8);
                    acc[mt][0] = mfma16(af, wf[kt][0], acc[mt][0]);
                    acc[mt][1] = mfma16(af, wf[kt][1], acc[mt][1]);
                }
            }
            bar_pub();   // S2: yL reads done before hT overlay

            // prefetch next bt's y (in flight across GEMM2 + epilogues)
            if (s == 0 && l == 0) {
                const bf16_t* ybt1 = y + (size_t)(bt0 + 1) * kPD;
                #pragma unroll
                for (int i = 0; i < 6; ++i)
                    yP[i] = *(const bf16x8*)(ybt1 + (ty * 6 + i) * kD + d0);
                __builtin_amdgcn_sched_barrier(0);
            }

            // write h transposed: hT[e][p]
            #pragma unroll
            for (int mt = 0; mt < 6; ++mt)
                #pragma unroll
                for (int nn = 0; nn < 2; ++nn) {
                    int e = (w * 2 + nn) * 16 + fc;
                    int p0 = mt * 16 + fg * 4;
                    bf16x4 hv = {(bf16_t)acc[mt][nn][0], (bf16_t)acc[mt][nn][1],
                                 (bf16_t)acc[mt][nn][2], (bf16_t)acc[mt][nn][3]};
                    *(bf16x4*)(hT + e * HS + p0) = hv;
                }
            bar_pub();   // S3: hT visible

            // ---- GEMM2: o = aL * h^T  (K=96) ----
            f32x4 acc2[6][2];
            #pragma unroll
            for (int mt = 0; mt < 6; ++mt) { acc2[mt][0] = {0,0,0,0}; acc2[mt][1] = {0,0,0,0}; }
            #pragma unroll
            for (int kt = 0; kt < 3; ++kt) {
                bf16x8 bf0 = *(const bf16x8*)(hT + (w * 32 + fc) * HS + kt * 32 + fg * 8);
                bf16x8 bf1 = *(const bf16x8*)(hT + (w * 32 + 16 + fc) * HS + kt * 32 + fg * 8);
                #pragma unroll
                for (int mt = 0; mt < 6; ++mt) {
                    bf16x8 af = *(const bf16x8*)(aL + (mt * 16 + fc) * AS + kt * 32 + fg * 8);
                    acc2[mt][0] = mfma16(af, bf0, acc2[mt][0]);
                    acc2[mt][1] = mfma16(af, bf1, acc2[mt][1]);
                }
            }
            bar_pub();   // S4: hT reads done before oLb overlay

            // scatter o -> oLb (bf16)
            #pragma unroll
            for (int mt = 0; mt < 6; ++mt)
                #pragma unroll
                for (int nn = 0; nn < 2; ++nn) {
                    int d = (w * 2 + nn) * 16 + fc;
                    int p0 = mt * 16 + fg * 4;
                    oLb[(p0 + 0) * OS + d] = (bf16_t)acc2[mt][nn][0];
                    oLb[(p0 + 1) * OS + d] = (bf16_t)acc2[mt][nn][1];
                    oLb[(p0 + 2) * OS + d] = (bf16_t)acc2[mt][nn][2];
                    oLb[(p0 + 3) * OS + d] = (bf16_t)acc2[mt][nn][3];
                }
            bar_pub();   // S5: oLb ready

            // ---- epilogue: relu+bias+mask, LN over D, residual update ----
            const float* pLl = pL + l * 384;
            float4 bb0 = *(const float4*)(pLl + d0);
            float4 bb1 = *(const float4*)(pLl + d0 + 4);
            float4 gg0 = *(const float4*)(pLl + 128 + d0);
            float4 gg1 = *(const float4*)(pLl + 128 + d0 + 4);
            float4 be0 = *(const float4*)(pLl + 256 + d0);
            float4 be1 = *(const float4*)(pLl + 256 + d0 + 4);
            float bb[8] = {bb0.x, bb0.y, bb0.z, bb0.w, bb1.x, bb1.y, bb1.z, bb1.w};
            float gg[8] = {gg0.x, gg0.y, gg0.z, gg0.w, gg1.x, gg1.y, gg1.z, gg1.w};
            float be[8] = {be0.x, be0.y, be0.z, be0.w, be1.x, be1.y, be1.z, be1.w};

            #pragma unroll
            for (int i = 0; i < 6; ++i) {
                int p = ty * 6 + i;
                float mpf = mrowf[p];
                bf16x4 o0 = *(const bf16x4*)(oLb + p * OS + d0);
                bf16x4 o1 = *(const bf16x4*)(oLb + p * OS + d0 + 4);
                float v[8];
                #pragma unroll
                for (int j = 0; j < 4; ++j) {
                    v[j]     = fmaxf((float)o0[j] + bb[j], 0.f) * mpf;
                    v[j + 4] = fmaxf((float)o1[j] + bb[j + 4], 0.f) * mpf;
                }
                float sm = v[0] + v[1] + v[2] + v[3] + v[4] + v[5] + v[6] + v[7];
                sm += __shfl_xor(sm, 8);
                sm += __shfl_xor(sm, 4);
                sm += __shfl_xor(sm, 2);
                sm += __shfl_xor(sm, 1);
                float mu = sm * 0.0078125f;

                float ss = 0.f;
                #pragma unroll
                for (int j = 0; j < 8; ++j) { float dv = v[j] - mu; ss += dv * dv; }
                ss += __shfl_xor(ss, 8);
                ss += __shfl_xor(ss, 4);
                ss += __shfl_xor(ss, 2);
                ss += __shfl_xor(ss, 1);
                float inv = rsqrtf(ss * 0.0078125f + 1e-5f);

                #pragma unroll
                for (int j = 0; j < 8; ++j)
                    res[i][j] += (v[j] - mu) * inv * gg[j] + be[j];
            }

            if (l == 0) {
                bar_pub();   // S6: oLb reads done before yL restage
                #pragma unroll
                for (int i = 0; i < 6; ++i) {
                    int p = ty * 6 + i;
                    bf16x8 c;
                    #pragma unroll
                    for (int j = 0; j < 8; ++j) c[j] = (bf16_t)res[i][j];
                    *(bf16x8*)(yL + p * YS + d0) = c;
                }
                // next S1 publishes
            }
        }

        // store final residual (global, no wait needed)
        #pragma unroll
        for (int i = 0; i < 6; ++i) {
            int p = ty * 6 + i;
            bf16x8 c;
            #pragma unroll
            for (int j = 0; j < 8; ++j) c[j] = (bf16_t)res[i][j];
            *(bf16x8*)(ybt + p * kD + d0) = c;
        }

        if (s == 0) bar_pub();  // all oLb/mrowf reads done before next staging
    }
}

// ---------------------------------------------------------------------------
extern "C" void kernel_launch(void* const* d_in, const int* in_sizes, int n_in,
                              void* d_out, int out_size, void* d_ws, size_t ws_size,
                              hipStream_t stream) {
    (void)in_sizes; (void)n_in; (void)out_size; (void)ws_size;

    const float* x = (const float*)d_in[0];
    const float* dist = (const float*)d_in[1];
    const unsigned char* mraw = (const unsigned char*)d_in[2];
    const float* W = (const float*)d_in[3];
    const float* bias = (const float*)d_in[4];
    const float* gamma = (const float*)d_in[5];
    const float* beta = (const float*)d_in[6];
    float* out = (float*)d_out;

    char* ws = (char*)d_ws;
    double* stats = (double*)ws;                            // 32 B
    float* params = (float*)(ws + 32);                      // 16 B
    int* mask = (int*)(ws + 64);                            // 6144 B
    float* ppack = (float*)(ws + 8192);                     // 3072 B
    bf16_t* wT = (bf16_t*)(ws + 16384);                     // 65,536 B
    bf16_t* adj = (bf16_t*)(ws + 81920);                    // 35,389,440 B
    bf16_t* y = (bf16_t*)(ws + 81920 + (size_t)kBT * kPP * 2);  // 47,185,920 B

    k_mask<<<1, 256, 0, stream>>>(mraw, mask, stats, bias, gamma, beta, ppack);
    k_prep<<<dim3(64, 2), 256, 0, stream>>>(W, wT);
    k_stats<<<1024, 256, 0, stream>>>(dist, mask, stats);
    k_fin<<<1, 1, 0, stream>>>(stats, params);
    k_adj<<<kBT, 256, 0, stream>>>(dist, mask, params, adj);

    k_tin<<<dim3(kPD / 64, kB), 256, 0, stream>>>(x, y);

    k_gcn<<<kBT / 2, 256, 0, stream>>>(y, adj, mask, wT, ppack);

    k_tout<<<dim3(kPD / 64, kB), 256, 0, stream>>>(y, out);
}

// Round 5
// 192.492 us; speedup vs baseline: 1.5899x; 1.5899x over previous
//
#include <hip/hip_runtime.h>
#include <math.h>

typedef __bf16 bf16_t;
typedef __bf16 bf16x8 __attribute__((ext_vector_type(8)));
typedef __bf16 bf16x4 __attribute__((ext_vector_type(4)));
typedef float f32x4 __attribute__((ext_vector_type(4)));

namespace {
constexpr int kB = 16;
constexpr int kT = 120;
constexpr int kP = 96;
constexpr int kD = 128;
constexpr int kBT = kB * kT;        // 1920
constexpr int kPP = kP * kP;        // 9216
constexpr int kPD = kP * kD;        // 12288
constexpr long long kND = (long long)kBT * kPP;  // 17,694,720

// LDS strides (bf16 elements) for k_gcn
constexpr int YS = 136;   // yL  [96][136]  = 26112 B
constexpr int HS = 104;   // hT  [128][104] = 26624 B
constexpr int OS = 132;   // oLb [96][132]  = 25344 B
constexpr int AS = 104;   // aL  [96][104]  = 19968 B
constexpr int UNION_B = 26624;             // max(yL, hT, oLb)
constexpr int AL_OFF = UNION_B;            // 26624
constexpr int MROW_OFF = AL_OFF + 19968;   // 46592
constexpr int SMEM_B = MROW_OFF + 384;     // 46976 -> 3 blocks/CU
}

__device__ __forceinline__ f32x4 mfma16(bf16x8 a, bf16x8 b, f32x4 c) {
    return __builtin_amdgcn_mfma_f32_16x16x32_bf16(a, b, c, 0, 0, 0);
}

// ---------------------------------------------------------------------------
// Kernel 1: canonicalize padding mask (layout-detecting) + zero stats accums.
// ---------------------------------------------------------------------------
__global__ void k_mask(const unsigned char* __restrict__ mraw, int* __restrict__ mask,
                       double* __restrict__ stats) {
    int tid = threadIdx.x;
    if (tid < 4) stats[tid] = 0.0;
    const unsigned int* u32 = (const unsigned int*)mraw;
    unsigned int w0 = u32[0];
    int mode;
    if (w0 == 0x01010101u) mode = 0;       // 1-byte bool
    else if (w0 == 1u) mode = 1;           // int32
    else mode = 2;                          // float32
    for (int i = tid; i < kB * kP; i += blockDim.x) {
        int v;
        if (mode == 0)      v = (mraw[i] != 0);
        else if (mode == 1) v = (u32[i] != 0);
        else                v = (((const float*)mraw)[i] != 0.0f);
        mask[i] = v;
    }
}

// ---------------------------------------------------------------------------
// Kernel 2: W[l][k][n] (f32) -> wT[l][n][k] (bf16)
// ---------------------------------------------------------------------------
__global__ void k_prep(const float* __restrict__ W, bf16_t* __restrict__ wT) {
    int l = blockIdx.y;
    int idx = blockIdx.x * 256 + threadIdx.x;
    int n = idx >> 7, k = idx & 127;
    wT[l * 16384 + n * 128 + k] = (bf16_t)W[l * 16384 + k * 128 + n];
}

// ---------------------------------------------------------------------------
// Kernel 3: global masked stats over distances (float4 loads, LDS mask).
// ---------------------------------------------------------------------------
__global__ __launch_bounds__(256) void k_stats(const float* __restrict__ dist,
                                               const int* __restrict__ mask,
                                               double* __restrict__ stats) {
    __shared__ int ml[kB * kP];
    for (int i = threadIdx.x; i < kB * kP; i += 256) ml[i] = mask[i];
    __syncthreads();

    long long n4 = kND / 4;
    long long stride = (long long)gridDim.x * 256;
    double s = 0.0, s2 = 0.0;
    int cnt = 0;
    for (long long i4 = (long long)blockIdx.x * 256 + threadIdx.x; i4 < n4; i4 += stride) {
        int q0 = 4 * (int)(i4 % 24);
        long long r = i4 / 24;
        int p = (int)(r % 96);
        int b = (int)((r / 96) / kT);
        const int* mb = ml + b * kP;
        if (mb[p]) {
            float4 d4 = *(const float4*)(dist + i4 * 4);
            if (mb[q0 + 0]) { s += d4.x; s2 += (double)d4.x * d4.x; cnt++; }
            if (mb[q0 + 1]) { s += d4.y; s2 += (double)d4.y * d4.y; cnt++; }
            if (mb[q0 + 2]) { s += d4.z; s2 += (double)d4.z * d4.z; cnt++; }
            if (mb[q0 + 3]) { s += d4.w; s2 += (double)d4.w * d4.w; cnt++; }
        }
    }
    __shared__ double sh[256];
    int tid = threadIdx.x;
    sh[tid] = s; __syncthreads();
    for (int off = 128; off > 0; off >>= 1) { if (tid < off) sh[tid] += sh[tid + off]; __syncthreads(); }
    if (tid == 0) atomicAdd(&stats[0], sh[0]);
    __syncthreads();
    sh[tid] = s2; __syncthreads();
    for (int off = 128; off > 0; off >>= 1) { if (tid < off) sh[tid] += sh[tid + off]; __syncthreads(); }
    if (tid == 0) atomicAdd(&stats[1], sh[0]);
    __syncthreads();
    sh[tid] = (double)cnt; __syncthreads();
    for (int off = 128; off > 0; off >>= 1) { if (tid < off) sh[tid] += sh[tid + off]; __syncthreads(); }
    if (tid == 0) atomicAdd(&stats[2], sh[0]);
}

// ---------------------------------------------------------------------------
// Kernel 4: finalize sigma -> 1/(2*sigma^2)
// ---------------------------------------------------------------------------
__global__ void k_fin(const double* __restrict__ stats, float* __restrict__ params) {
    double n = stats[2];
    double mean = stats[0] / n;
    double var = (stats[1] - n * mean * mean) / (n - 1.0);
    double sigma = sqrt(var) + 1e-8;
    params[0] = (float)(1.0 / (2.0 * sigma * sigma));
}

// ---------------------------------------------------------------------------
// Kernel 5: adjacency build, one block per (b,t). float4 in, bf16x4 out.
// Pre-normalization matrix is exactly symmetric (dist bitwise-symmetric),
// so degree = column sum (conflict-free LDS reads).
// ---------------------------------------------------------------------------
__global__ __launch_bounds__(256) void k_adj(const float* __restrict__ dist,
                                             const int* __restrict__ mask,
                                             const float* __restrict__ params,
                                             bf16_t* __restrict__ adj) {
    __shared__ float aT[kP * 100];
    __shared__ float dis[kP];
    __shared__ float mr[kP];
    int bt = blockIdx.x;
    int b = bt / kT;
    int tid = threadIdx.x;
    if (tid < kP) mr[tid] = (float)mask[b * kP + tid];
    float inv2s2 = params[0];
    __syncthreads();
    const float* dbt = dist + (long long)bt * kPP;
    #pragma unroll
    for (int k = 0; k < 9; ++k) {
        int i4 = k * 256 + tid;          // 0..2303
        int e = i4 * 4;
        int p = e / kP, q = e - p * kP;  // 96 % 4 == 0 -> same row
        float4 d4 = *(const float4*)(dbt + e);
        float mp = mr[p];
        float v[4];
        v[0] = mp * mr[q + 0] != 0.f ? __expf(-d4.x * d4.x * inv2s2) : 0.f;
        v[1] = mp * mr[q + 1] != 0.f ? __expf(-d4.y * d4.y * inv2s2) : 0.f;
        v[2] = mp * mr[q + 2] != 0.f ? __expf(-d4.z * d4.z * inv2s2) : 0.f;
        v[3] = mp * mr[q + 3] != 0.f ? __expf(-d4.w * d4.w * inv2s2) : 0.f;
        #pragma unroll
        for (int j = 0; j < 4; ++j) {
            if (p == q + j) v[j] += mp;
            aT[p * 100 + q + j] = v[j];
        }
    }
    __syncthreads();
    if (tid < kP) {
        float s = 0.f;
        for (int q = 0; q < kP; ++q) s += aT[q * 100 + tid];  // column == row sum
        s = fmaxf(s, 1e-8f);
        s = fmaxf(s * mr[tid], 1e-8f);
        dis[tid] = rsqrtf(s);
    }
    __syncthreads();
    bf16_t* obt = adj + (long long)bt * kPP;
    #pragma unroll
    for (int k = 0; k < 9; ++k) {
        int i4 = k * 256 + tid;
        int e = i4 * 4;
        int p = e / kP, q = e - p * kP;
        float dp = dis[p];
        bf16x4 ov;
        #pragma unroll
        for (int j = 0; j < 4; ++j)
            ov[j] = (bf16_t)(dp * aT[p * 100 + q + j] * dis[q + j]);
        *(bf16x4*)(obt + e) = ov;
    }
}

// ---------------------------------------------------------------------------
// Kernel 6: transpose in, x (B, PD, T) f32 -> y (B, T, PD) bf16.
// Block: 64 pd-rows x full T. float4 reads, bf16x8 writes.
// ---------------------------------------------------------------------------
__global__ __launch_bounds__(256) void k_tin(const float* __restrict__ x,
                                             bf16_t* __restrict__ y) {
    __shared__ float tile[64 * 121];
    int b = blockIdx.y, pd0 = blockIdx.x * 64;
    int tid = threadIdx.x;
    const float* xb = x + ((long long)b * kPD + pd0) * kT;
    #pragma unroll
    for (int k = 0; k < 8; ++k) {
        int idx = k * 256 + tid;               // < 1920 = 64 rows * 30 float4
        if (idx < 1920) {
            int r = idx / 30, c = idx - r * 30;
            float4 v = *(const float4*)(xb + r * kT + c * 4);
            tile[r * 121 + c * 4 + 0] = v.x;
            tile[r * 121 + c * 4 + 1] = v.y;
            tile[r * 121 + c * 4 + 2] = v.z;
            tile[r * 121 + c * 4 + 3] = v.w;
        }
    }
    __syncthreads();
    bf16_t* yb = y + (long long)b * kT * kPD + pd0;
    #pragma unroll
    for (int k = 0; k < 4; ++k) {
        int idx = k * 256 + tid;               // < 960 = 120 t * 8 dgroups
        if (idx < 960) {
            int t = idx >> 3, dg = idx & 7;
            bf16x8 o;
            #pragma unroll
            for (int j = 0; j < 8; ++j) o[j] = (bf16_t)tile[(dg * 8 + j) * 121 + t];
            *(bf16x8*)(yb + (long long)t * kPD + dg * 8) = o;
        }
    }
}

// ---------------------------------------------------------------------------
// Kernel 8: transpose out, y (B, T, PD) bf16 -> out (B, PD, T) f32.
// ---------------------------------------------------------------------------
__global__ __launch_bounds__(256) void k_tout(const bf16_t* __restrict__ y,
                                              float* __restrict__ out) {
    __shared__ float tile[64 * 121];
    int b = blockIdx.y, pd0 = blockIdx.x * 64;
    int tid = threadIdx.x;
    const bf16_t* yb = y + (long long)b * kT * kPD + pd0;
    #pragma unroll
    for (int k = 0; k < 4; ++k) {
        int idx = k * 256 + tid;
        if (idx < 960) {
            int t = idx >> 3, dg = idx & 7;
            bf16x8 v = *(const bf16x8*)(yb + (long long)t * kPD + dg * 8);
            #pragma unroll
            for (int j = 0; j < 8; ++j) tile[(dg * 8 + j) * 121 + t] = (float)v[j];
        }
    }
    __syncthreads();
    float* ob = out + ((long long)b * kPD + pd0) * kT;
    #pragma unroll
    for (int k = 0; k < 8; ++k) {
        int idx = k * 256 + tid;
        if (idx < 1920) {
            int r = idx / 30, c = idx - r * 30;
            float4 v;
            v.x = tile[r * 121 + c * 4 + 0];
            v.y = tile[r * 121 + c * 4 + 1];
            v.z = tile[r * 121 + c * 4 + 2];
            v.w = tile[r * 121 + c * 4 + 3];
            *(float4*)(ob + r * kT + c * 4) = v;
        }
    }
}

// ---------------------------------------------------------------------------
// Kernel 7: fused 2-layer GCN, one block (4 waves) per (b,t), 3 blocks/CU.
// (round-3 structure: plain __syncthreads(), W fragments per layer,
//  LDS union yL/hT/oLb, aL persistent. Known-good at 59 us.)
// ---------------------------------------------------------------------------
__global__ __launch_bounds__(256, 3) void k_gcn(bf16_t* __restrict__ y,
                                                const bf16_t* __restrict__ adj,
                                                const int* __restrict__ mask,
                                                const bf16_t* __restrict__ wT,
                                                const float* __restrict__ bias,
                                                const float* __restrict__ gamma,
                                                const float* __restrict__ beta) {
    __shared__ __align__(16) char smem[SMEM_B];
    bf16_t* yL  = (bf16_t*)smem;                  // [96][YS]   (union)
    bf16_t* hT  = (bf16_t*)smem;                  // [128][HS]  (union)
    bf16_t* oLb = (bf16_t*)smem;                  // [96][OS]   (union)
    bf16_t* aL  = (bf16_t*)(smem + AL_OFF);       // [96][AS]
    float* mrowf = (float*)(smem + MROW_OFF);     // [96]

    const int tid = threadIdx.x;
    const int tx = tid & 15, ty = tid >> 4;
    const int lane = tid & 63, w = tid >> 6;
    const int fc = lane & 15, fg = lane >> 4;     // MFMA frag coords
    const int bt = blockIdx.x, b = bt / kT;
    const int d0 = tx * 8;                        // epilogue: 8 consecutive d

    bf16_t* ybt = y + (size_t)bt * kPD;
    const bf16_t* abt = adj + (size_t)bt * kPP;

    if (tid < kP) mrowf[tid] = (float)mask[b * kP + tid];

    // stage adj -> aL
    #pragma unroll
    for (int k = 0; k < 9; ++k) {
        int e4 = (k * 256 + tid) * 4;
        int p = e4 / kP, q = e4 - p * kP;
        *(bf16x4*)(aL + p * AS + q) = *(const bf16x4*)(abt + e4);
    }

    // stage y -> yL and res (f32 residual); row p = ty*6+i, cols d0..d0+7
    float res[6][8];
    #pragma unroll
    for (int i = 0; i < 6; ++i) {
        int p = ty * 6 + i;
        bf16x8 v = *(const bf16x8*)(ybt + p * kD + d0);
        #pragma unroll
        for (int j = 0; j < 8; ++j) res[i][j] = (float)v[j];
        *(bf16x8*)(yL + p * YS + d0) = v;
    }

    for (int l = 0; l < 2; ++l) {
        // W fragments -> registers (before barrier; overlaps with it)
        const bf16_t* wTl = wT + l * kD * kD;
        bf16x8 wf[4][2];
        #pragma unroll
        for (int kt = 0; kt < 4; ++kt) {
            wf[kt][0] = *(const bf16x8*)(wTl + (w * 32 + fc) * kD + kt * 32 + fg * 8);
            wf[kt][1] = *(const bf16x8*)(wTl + (w * 32 + 16 + fc) * kD + kt * 32 + fg * 8);
        }
        __syncthreads();   // [S1] yL (and aL, l=0) ready

        // ---- GEMM1: h = yL * W  (K=128), no barriers inside ----
        f32x4 acc[6][2];
        #pragma unroll
        for (int mt = 0; mt < 6; ++mt) { acc[mt][0] = {0,0,0,0}; acc[mt][1] = {0,0,0,0}; }
        #pragma unroll
        for (int kt = 0; kt < 4; ++kt) {
            #pragma unroll
            for (int mt = 0; mt < 6; ++mt) {
                bf16x8 af = *(const bf16x8*)(yL + (mt * 16 + fc) * YS + kt * 32 + fg * 8);
                acc[mt][0] = mfma16(af, wf[kt][0], acc[mt][0]);
                acc[mt][1] = mfma16(af, wf[kt][1], acc[mt][1]);
            }
        }
        __syncthreads();   // [S2] yL reads done before hT overlay

        // write h transposed: hT[e][p]
        #pragma unroll
        for (int mt = 0; mt < 6; ++mt)
            #pragma unroll
            for (int nn = 0; nn < 2; ++nn) {
                int e = (w * 2 + nn) * 16 + fc;
                int p0 = mt * 16 + fg * 4;
                bf16x4 hv = {(bf16_t)acc[mt][nn][0], (bf16_t)acc[mt][nn][1],
                             (bf16_t)acc[mt][nn][2], (bf16_t)acc[mt][nn][3]};
                *(bf16x4*)(hT + e * HS + p0) = hv;
            }
        __syncthreads();   // [S3] hT ready

        // ---- GEMM2: o = aL * h^T  (K=96) ----
        f32x4 acc2[6][2];
        #pragma unroll
        for (int mt = 0; mt < 6; ++mt) { acc2[mt][0] = {0,0,0,0}; acc2[mt][1] = {0,0,0,0}; }
        #pragma unroll
        for (int kt = 0; kt < 3; ++kt) {
            bf16x8 bf0 = *(const bf16x8*)(hT + (w * 32 + fc) * HS + kt * 32 + fg * 8);
            bf16x8 bf1 = *(const bf16x8*)(hT + (w * 32 + 16 + fc) * HS + kt * 32 + fg * 8);
            #pragma unroll
            for (int mt = 0; mt < 6; ++mt) {
                bf16x8 af = *(const bf16x8*)(aL + (mt * 16 + fc) * AS + kt * 32 + fg * 8);
                acc2[mt][0] = mfma16(af, bf0, acc2[mt][0]);
                acc2[mt][1] = mfma16(af, bf1, acc2[mt][1]);
            }
        }
        __syncthreads();   // [S4] hT reads done before oLb overlay

        // scatter o -> oLb (bf16)
        #pragma unroll
        for (int mt = 0; mt < 6; ++mt)
            #pragma unroll
            for (int nn = 0; nn < 2; ++nn) {
                int d = (w * 2 + nn) * 16 + fc;
                int p0 = mt * 16 + fg * 4;
                oLb[(p0 + 0) * OS + d] = (bf16_t)acc2[mt][nn][0];
                oLb[(p0 + 1) * OS + d] = (bf16_t)acc2[mt][nn][1];
                oLb[(p0 + 2) * OS + d] = (bf16_t)acc2[mt][nn][2];
                oLb[(p0 + 3) * OS + d] = (bf16_t)acc2[mt][nn][3];
            }
        __syncthreads();   // [S5] oLb ready

        // ---- epilogue: relu+bias+mask, LN over D, residual update ----
        const float* bl = bias + l * kD;
        const float* gl = gamma + l * kD;
        const float* bel = beta + l * kD;
        float4 bb0 = *(const float4*)(bl + d0), bb1 = *(const float4*)(bl + d0 + 4);
        float4 gg0 = *(const float4*)(gl + d0), gg1 = *(const float4*)(gl + d0 + 4);
        float4 be0 = *(const float4*)(bel + d0), be1 = *(const float4*)(bel + d0 + 4);
        float bb[8] = {bb0.x, bb0.y, bb0.z, bb0.w, bb1.x, bb1.y, bb1.z, bb1.w};
        float gg[8] = {gg0.x, gg0.y, gg0.z, gg0.w, gg1.x, gg1.y, gg1.z, gg1.w};
        float be[8] = {be0.x, be0.y, be0.z, be0.w, be1.x, be1.y, be1.z, be1.w};

        #pragma unroll
        for (int i = 0; i < 6; ++i) {
            int p = ty * 6 + i;
            float mpf = mrowf[p];
            bf16x4 o0 = *(const bf16x4*)(oLb + p * OS + d0);
            bf16x4 o1 = *(const bf16x4*)(oLb + p * OS + d0 + 4);
            float v[8];
            #pragma unroll
            for (int j = 0; j < 4; ++j) {
                v[j]     = fmaxf((float)o0[j] + bb[j], 0.f) * mpf;
                v[j + 4] = fmaxf((float)o1[j] + bb[j + 4], 0.f) * mpf;
            }
            float s = v[0] + v[1] + v[2] + v[3] + v[4] + v[5] + v[6] + v[7];
            s += __shfl_xor(s, 8);
            s += __shfl_xor(s, 4);
            s += __shfl_xor(s, 2);
            s += __shfl_xor(s, 1);
            float mu = s * 0.0078125f;

            float ss = 0.f;
            #pragma unroll
            for (int j = 0; j < 8; ++j) { float dv = v[j] - mu; ss += dv * dv; }
            ss += __shfl_xor(ss, 8);
            ss += __shfl_xor(ss, 4);
            ss += __shfl_xor(ss, 2);
            ss += __shfl_xor(ss, 1);
            float inv = rsqrtf(ss * 0.0078125f + 1e-5f);

            #pragma unroll
            for (int j = 0; j < 8; ++j)
                res[i][j] += (v[j] - mu) * inv * gg[j] + be[j];
        }

        if (l == 0) {
            __syncthreads();   // [S6] oLb reads done before yL overlay restage
            #pragma unroll
            for (int i = 0; i < 6; ++i) {
                int p = ty * 6 + i;
                bf16x8 c;
                #pragma unroll
                for (int j = 0; j < 8; ++j) c[j] = (bf16_t)res[i][j];
                *(bf16x8*)(yL + p * YS + d0) = c;
            }
            // next layer's [S1] makes these visible
        } else {
            #pragma unroll
            for (int i = 0; i < 6; ++i) {
                int p = ty * 6 + i;
                bf16x8 c;
                #pragma unroll
                for (int j = 0; j < 8; ++j) c[j] = (bf16_t)res[i][j];
                *(bf16x8*)(ybt + p * kD + d0) = c;
            }
        }
    }
}

// ---------------------------------------------------------------------------
extern "C" void kernel_launch(void* const* d_in, const int* in_sizes, int n_in,
                              void* d_out, int out_size, void* d_ws, size_t ws_size,
                              hipStream_t stream) {
    (void)in_sizes; (void)n_in; (void)out_size; (void)ws_size;

    const float* x = (const float*)d_in[0];
    const float* dist = (const float*)d_in[1];
    const unsigned char* mraw = (const unsigned char*)d_in[2];
    const float* W = (const float*)d_in[3];
    const float* bias = (const float*)d_in[4];
    const float* gamma = (const float*)d_in[5];
    const float* beta = (const float*)d_in[6];
    float* out = (float*)d_out;

    char* ws = (char*)d_ws;
    double* stats = (double*)ws;                            // 32 B
    float* params = (float*)(ws + 32);                      // 16 B
    int* mask = (int*)(ws + 64);                            // 6144 B
    bf16_t* wT = (bf16_t*)(ws + 8192);                      // 65,536 B
    bf16_t* adj = (bf16_t*)(ws + 81920);                    // 35,389,440 B
    bf16_t* y = (bf16_t*)(ws + 81920 + (size_t)kBT * kPP * 2);  // 47,185,920 B

    k_mask<<<1, 256, 0, stream>>>(mraw, mask, stats);
    k_prep<<<dim3(64, 2), 256, 0, stream>>>(W, wT);
    k_stats<<<1024, 256, 0, stream>>>(dist, mask, stats);
    k_fin<<<1, 1, 0, stream>>>(stats, params);
    k_adj<<<kBT, 256, 0, stream>>>(dist, mask, params, adj);

    k_tin<<<dim3(kPD / 64, kB), 256, 0, stream>>>(x, y);

    k_gcn<<<kBT, 256, 0, stream>>>(y, adj, mask, wT, bias, gamma, beta);

    k_tout<<<dim3(kPD / 64, kB), 256, 0, stream>>>(y, out);
}